// Round 1
// baseline (279.955 us; speedup 1.0000x reference)
//
#include <hip/hip_runtime.h>
#include <math.h>

#define NG 16
#define DIM 64
#define LOG_2PI 1.8378770664093453f
#define RPW 4                      // rows per wave
#define WPB 4                      // waves per block (256 threads)
#define ROWS_PER_BLOCK (RPW * WPB) // 16

// One WAVE per batch row (grid-strided over RPW consecutive rows).
// Lane l: gaussian g = l>>2, dim-quarter dq = l&3 (dims dq*16 .. dq*16+15).
// Each lane loads 4 contiguous float4s of means + 4 of covs (64 B each, all
// 8 loads independent and in flight together) + 4 float4s of the target row
// (L1-broadcast across the 16 quads) + its gaussian's weight.
// Whole-row reduction is pure shuffles: 2 xor-shuffles for the 64-dim quad
// sum, then a 16-wide logsumexp across quads via xor 4/8/16/32.
// No LDS, no __syncthreads, no single-wave serial tail -> each wave streams
// independently; 2048 blocks instead of 32768 removes the workgroup
// dispatch-rate bottleneck.
__global__ __launch_bounds__(256) void gmm_loss_kernel(
    const float* __restrict__ means,
    const float* __restrict__ covs,
    const float* __restrict__ weights,
    const float* __restrict__ targets,
    float* __restrict__ out, int B)
{
    const int lane = threadIdx.x & 63;
    const int wave = threadIdx.x >> 6;
    const int g  = lane >> 2;   // gaussian owned by this quad
    const int dq = lane & 3;    // which 16-dim quarter of the gaussian
    const int fo = lane * 4;    // first float4 index in the row for this lane

    int b = blockIdx.x * ROWS_PER_BLOCK + wave * RPW;

    #pragma unroll 1
    for (int r = 0; r < RPW; ++r, ++b) {
        if (b >= B) break;

        const float4* m4 = (const float4*)(means + (size_t)b * (NG * DIM)) + fo;
        const float4* v4 = (const float4*)(covs  + (size_t)b * (NG * DIM)) + fo;
        const float4* t4 = (const float4*)(targets + (size_t)b * DIM) + dq * 4;

        // all loads independent; issued back-to-back, one HBM round trip
        const float  w  = weights[(size_t)b * NG + g];
        const float4 m0 = m4[0], m1 = m4[1], m2 = m4[2], m3 = m4[3];
        const float4 v0 = v4[0], v1 = v4[1], v2 = v4[2], v3 = v4[3];
        const float4 t0 = t4[0], t1 = t4[1], t2 = t4[2], t3 = t4[3];

        float p = 0.0f;
        float dx;
        // quad-form + logdet, 16 dims per lane; log of 4-element product is
        // exact-safe (product in [0.0625, 5.06]) and matches the previous
        // verified kernel's numerics
        dx = t0.x - m0.x; p += dx * dx * __builtin_amdgcn_rcpf(v0.x);
        dx = t0.y - m0.y; p += dx * dx * __builtin_amdgcn_rcpf(v0.y);
        dx = t0.z - m0.z; p += dx * dx * __builtin_amdgcn_rcpf(v0.z);
        dx = t0.w - m0.w; p += dx * dx * __builtin_amdgcn_rcpf(v0.w);
        p += __logf(v0.x * v0.y * v0.z * v0.w);

        dx = t1.x - m1.x; p += dx * dx * __builtin_amdgcn_rcpf(v1.x);
        dx = t1.y - m1.y; p += dx * dx * __builtin_amdgcn_rcpf(v1.y);
        dx = t1.z - m1.z; p += dx * dx * __builtin_amdgcn_rcpf(v1.z);
        dx = t1.w - m1.w; p += dx * dx * __builtin_amdgcn_rcpf(v1.w);
        p += __logf(v1.x * v1.y * v1.z * v1.w);

        dx = t2.x - m2.x; p += dx * dx * __builtin_amdgcn_rcpf(v2.x);
        dx = t2.y - m2.y; p += dx * dx * __builtin_amdgcn_rcpf(v2.y);
        dx = t2.z - m2.z; p += dx * dx * __builtin_amdgcn_rcpf(v2.z);
        dx = t2.w - m2.w; p += dx * dx * __builtin_amdgcn_rcpf(v2.w);
        p += __logf(v2.x * v2.y * v2.z * v2.w);

        dx = t3.x - m3.x; p += dx * dx * __builtin_amdgcn_rcpf(v3.x);
        dx = t3.y - m3.y; p += dx * dx * __builtin_amdgcn_rcpf(v3.y);
        dx = t3.z - m3.z; p += dx * dx * __builtin_amdgcn_rcpf(v3.z);
        dx = t3.w - m3.w; p += dx * dx * __builtin_amdgcn_rcpf(v3.w);
        p += __logf(v3.x * v3.y * v3.z * v3.w);

        // sum the 4 dim-quarters of this gaussian (lanes 4g..4g+3)
        p += __shfl_xor(p, 1);
        p += __shfl_xor(p, 2);

        float lp = -0.5f * (DIM * LOG_2PI + p);
        lp = fminf(fmaxf(lp, -100.0f), 0.0f);
        const float lw = lp + __logf(w);

        // logsumexp over the 16 gaussians (one representative lane per quad
        // in each xor-tree; lane&3 is invariant under strides 4/8/16/32)
        float M = lw;
        M = fmaxf(M, __shfl_xor(M, 4));
        M = fmaxf(M, __shfl_xor(M, 8));
        M = fmaxf(M, __shfl_xor(M, 16));
        M = fmaxf(M, __shfl_xor(M, 32));
        float e = __expf(lw - M);
        e += __shfl_xor(e, 4);
        e += __shfl_xor(e, 8);
        e += __shfl_xor(e, 16);
        e += __shfl_xor(e, 32);

        if (lane == 0) out[b] = -(M + __logf(e));
    }
}

extern "C" void kernel_launch(void* const* d_in, const int* in_sizes, int n_in,
                              void* d_out, int out_size, void* d_ws, size_t ws_size,
                              hipStream_t stream) {
    const float* means   = (const float*)d_in[0];
    const float* covs    = (const float*)d_in[1];
    const float* weights = (const float*)d_in[2];
    const float* targets = (const float*)d_in[3];
    float* out = (float*)d_out;

    const int B = in_sizes[0] / (NG * DIM);                 // 32768
    const int grid = (B + ROWS_PER_BLOCK - 1) / ROWS_PER_BLOCK;  // 2048
    gmm_loss_kernel<<<grid, 256, 0, stream>>>(means, covs, weights, targets, out, B);
}